// Round 7
// baseline (1322.580 us; speedup 1.0000x reference)
//
#include <hip/hip_runtime.h>

// psRNN round 14: r13 wide-publish experiment, compile-fixed (f32x4 ext-vector
// instead of HIP float4 struct for the asm "v" input operand; clang can't
// pass struct inputs to reg-tuple constraints, though outputs are fine).
// Theory unchanged from r13: the never-varied chain leg is the PRODUCER side
// -- r7 publishes 1024 scattered 2B stores/block then vmcnt(0)-drains them
// all before flagging (WRITE_SIZE=141MB/dispatch shows write-through + RMW).
// Fix: combine packs s2/c2 into LDS (same index math as the global layout,
// consumers untouched), one extra __syncthreads, then ONE dwordx4 per wave
// (w0:StB.s sc1, w1:StB.c sc1, w2:StA.s sc0, w3:StA.c sc0), ONE ack, flag.
// Predicted: main ~930us / total ~1030us, MfmaUtil ~18%, FETCH < 126MB.
// Neutral => producer at floor => communication roofline.

typedef _Float16 half_t;
typedef _Float16 half8 __attribute__((ext_vector_type(8)));
typedef float f32x4 __attribute__((ext_vector_type(4)));

#define NHID 2048
#define NOUT 64
#define ST_UNIT 65536   // halfs per (buf,rep): s [0,32768) + c [32768,65536)
#define N_ROUNDS 256

#define MFMA16(A, B, C) __builtin_amdgcn_mfma_f32_16x16x32_f16(A, B, C, 0, 0, 0)

// ws layout (bytes):
//   [0, 4096)       : flags  uint[4][256]  ([rep][slot*4+wave], monotonic)
//   [4096, 4160)    : roster uint[8]       (per-XCD block counter)
//   [1M, 1M+1.5M)   : StA  half[3][4][ST_UNIT]  (sc0 / XCD-L2 copy)
//   [3M, 3M+1.5M)   : StB  half[3][4][ST_UNIT]  (sc1 / LLC copy)
//   [8M, 16M)       : WT16 half[2048][2048]     (W transposed, f16; dead after w2)
//   [16M, 24M)      : W2   half[2048][2048]

__device__ __forceinline__ half8 cvt8(float4 lo, float4 hi) {
  half8 h;
  h[0] = (half_t)lo.x; h[1] = (half_t)lo.y; h[2] = (half_t)lo.z; h[3] = (half_t)lo.w;
  h[4] = (half_t)hi.x; h[5] = (half_t)hi.y; h[6] = (half_t)hi.z; h[7] = (half_t)hi.w;
  return h;
}

__global__ void psrnn_init_kernel(unsigned* flags, unsigned* roster,
                                  uint4* stA, uint4* stB) {
  int g = blockIdx.x * blockDim.x + threadIdx.x;  // 16384 threads
  uint4 v; v.x = 0x3C003C00u; v.y = 0x3C003C00u; v.z = 0x3C003C00u; v.w = 0x3C003C00u;
  const int rep = g >> 12, local = g & 4095;      // buf0 s := fp16 1.0, both copies
  stA[rep * (ST_UNIT / 8) + local] = v;
  stB[rep * (ST_UNIT / 8) + local] = v;
  if (g < 1024) flags[g] = 0;
  else if (g < 1032) roster[g - 1024] = 0;
}

// W (fp32 row-major) -> WT16 (f16, transposed, row-major)
__global__ __launch_bounds__(256) void psrnn_conv_kernel(
    const float* __restrict__ Wh, half_t* __restrict__ WT16) {
  __shared__ float tile[64][65];
  const int bi = blockIdx.x & 31, bj = blockIdx.x >> 5;
  const int rs = threadIdx.x >> 6, c = threadIdx.x & 63;
#pragma unroll
  for (int i = 0; i < 16; ++i) {
    const int row = rs * 16 + i;
    tile[row][c] = Wh[(size_t)(bi * 64 + row) * NHID + bj * 64 + c];
  }
  __syncthreads();
#pragma unroll
  for (int i = 0; i < 16; ++i) {
    const int row = rs * 16 + i;
    WT16[(size_t)(bj * 64 + row) * NHID + bi * 64 + c] = (half_t)tile[c][row];
  }
}

// W2 = f16( f16(W) @ f16(W) ), 128x128 tiles, B-chunk staged in LDS.
__global__ __launch_bounds__(256) void psrnn_w2_kernel(
    const float* __restrict__ Wh, const half_t* __restrict__ WT16,
    half_t* __restrict__ W2) {
  __shared__ half_t Bs[128][40];  // pad 40: 16B-aligned frags, spread banks
  const int bi = blockIdx.x & 15, bj = blockIdx.x >> 4;
  const int tid = threadIdx.x, w = tid >> 6, lane = tid & 63;
  const int lm = lane & 15, kg = lane >> 4;
  const int brow = tid >> 2, bseg = tid & 3;

  f32x4 acc[2][8];
#pragma unroll
  for (int mt = 0; mt < 2; ++mt)
#pragma unroll
    for (int nt = 0; nt < 8; ++nt) acc[mt][nt] = (f32x4){0.f, 0.f, 0.f, 0.f};

  for (int c = 0; c < 64; ++c) {
    __syncthreads();
#pragma unroll
    for (int i = 0; i < 2; ++i) {
      const int row = brow + i * 64;
      *(half8*)&Bs[row][bseg * 8] =
          *(const half8*)(WT16 + (size_t)(bj * 128 + row) * NHID + c * 32 + bseg * 8);
    }
    __syncthreads();
    const float* pa0 = Wh + (size_t)(bi * 128 + w * 32 + lm) * NHID + c * 32 + kg * 8;
    const float* pa1 = pa0 + (size_t)16 * NHID;
    half8 a0 = cvt8(*(const float4*)pa0, *(const float4*)(pa0 + 4));
    half8 a1 = cvt8(*(const float4*)pa1, *(const float4*)(pa1 + 4));
#pragma unroll
    for (int nt = 0; nt < 8; ++nt) {
      half8 b = *(const half8*)&Bs[nt * 16 + lm][kg * 8];
      acc[0][nt] = MFMA16(a0, b, acc[0][nt]);
      acc[1][nt] = MFMA16(a1, b, acc[1][nt]);
    }
  }
#pragma unroll
  for (int mt = 0; mt < 2; ++mt)
#pragma unroll
    for (int nt = 0; nt < 8; ++nt)
#pragma unroll
      for (int r = 0; r < 4; ++r)
        W2[(size_t)(bi * 128 + w * 32 + mt * 16 + kg * 4 + r) * NHID +
           bj * 128 + nt * 16 + lm] = (half_t)acc[mt][nt][r];
}

__global__ __launch_bounds__(256, 1) void psrnn_main_kernel(
    const float* __restrict__ x,      // [512][64][64]
    const float* __restrict__ Wi_w,   // [2048][64]
    const float* __restrict__ Wi_b,   // [2048]
    const float* __restrict__ Wh_w,   // [2048][2048]
    const float* __restrict__ Av,     // [2048]
    const float* __restrict__ Om,     // [2048]
    const half_t* __restrict__ W2,    // [2048][2048] f16
    unsigned* __restrict__ flags,
    unsigned* __restrict__ roster,
    half_t* __restrict__ StA,         // sc0 / XCD-L2 copy
    half_t* __restrict__ StB)         // sc1 / LLC copy
{
  extern __shared__ char lds_force[];        // +40KB dyn: forces 1 block/CU
  __shared__ float ybuf[2][4][2][2][16][18]; // [par][wave][arr][nt][m][n]
  __shared__ float ubuf[2][2][2][16][18];    // [par][t'][nt][m][n]
  __shared__ half_t pbufS[512];              // packed s2 (slot-local layout)
  __shared__ half_t pbufC[512];              // packed c2
  __shared__ unsigned slot_sh;
  (void)lds_force;

  const int tid = threadIdx.x, w = tid >> 6, lane = tid & 63;
  const int lm = lane & 15, kg = lane >> 4;

  unsigned xcd;
  asm volatile("s_getreg_b32 %0, hwreg(HW_REG_XCC_ID)" : "=s"(xcd));
  const int rep    = (int)(xcd & 3u);
  const int halfId = (int)((xcd >> 2) & 1u);
  if (tid == 0) slot_sh = (unsigned)(halfId * 32) + (atomicAdd(&roster[xcd & 7u], 1u) & 31u);
  __syncthreads();
  const int slot = (int)slot_sh;
  const int n0 = slot * 32, b0 = rep * 16;
  const bool locw = ((w >> 1) == halfId);  // my producers are on my XCD
  const int tpar = w >> 1, ntu = w & 1;    // u-duty: wave -> (timestep, nt)

  // ---- W, W2 B-frags: rows n0+16nt+lm, K = 512w + 32c + kg*8..
  half8 wb[2][16], w2b[2][16];
#pragma unroll
  for (int nt = 0; nt < 2; ++nt)
#pragma unroll
    for (int c = 0; c < 16; ++c) {
      const float* p = Wh_w + (size_t)(n0 + nt * 16 + lm) * NHID + (w * 512 + c * 32 + kg * 8);
      wb[nt][c] = cvt8(*(const float4*)p, *(const float4*)(p + 4));
      w2b[nt][c] = *(const half8*)(W2 + (size_t)(n0 + nt * 16 + lm) * NHID +
                                   (w * 512 + c * 32 + kg * 8));
    }
  half8 wi0, wi1;
  {
    const float* p = Wi_w + (size_t)(n0 + ntu * 16 + lm) * 64 + kg * 8;
    wi0 = cvt8(*(const float4*)p, *(const float4*)(p + 4));
    wi1 = cvt8(*(const float4*)(p + 32), *(const float4*)(p + 36));
  }

  // ---- combiner constants: thread owns (batch m, neurons n0+nt*16+nn)
  const int m = tid >> 4, nn = tid & 15;
  float cA2[2], cOm2[2], cB2[2];
  int off2[2], pix2[2];
#pragma unroll
  for (int nt = 0; nt < 2; ++nt) {
    const int ng = n0 + nt * 16 + nn;
    cA2[nt] = Av[ng]; cOm2[nt] = Om[ng]; cB2[nt] = Wi_b[ng];
    pix2[nt] = (nt * 2 + (nn >> 3)) * 128 + m * 8 + (nn & 7);
    off2[nt] = slot * 512 + pix2[nt];
  }
  float cpr[2];

  unsigned* const pollp = flags + rep * 256 + w * 64 + lane;  // 64 producer waves
  unsigned* const myf   = flags + rep * 256 + slot * 4 + w;

  // ---- preloop: u_0 (waves 0,1), publish c_0 to buf0 (both copies), flag=1
  if (w < 2) {
    const float* xp = x + (size_t)(b0 + lm) * 64;
    float4 a0 = *(const float4*)(xp + kg * 8), a1 = *(const float4*)(xp + kg * 8 + 4);
    float4 a2 = *(const float4*)(xp + 32 + kg * 8), a3 = *(const float4*)(xp + 36 + kg * 8);
    f32x4 au = {0.f, 0.f, 0.f, 0.f};
    au = MFMA16(cvt8(a0, a1), wi0, au);
    au = MFMA16(cvt8(a2, a3), wi1, au);
#pragma unroll
    for (int r = 0; r < 4; ++r) ubuf[0][0][ntu][kg * 4 + r][lm] = au[r];
  }
  __syncthreads();
  {
    half_t* cA_ = StA + (size_t)rep * ST_UNIT + 32768;
    half_t* cB_ = StB + (size_t)rep * ST_UNIT + 32768;
#pragma unroll
    for (int nt = 0; nt < 2; ++nt) {
      const float u0 = ubuf[0][0][nt][m][nn] + cB2[nt];
      cpr[nt] = cA2[nt] * __cosf(cOm2[nt] * 1.0f + u0);
      unsigned hv = (unsigned)__builtin_bit_cast(unsigned short, (half_t)cpr[nt]);
      const half_t* pA = cA_ + off2[nt];
      const half_t* pB = cB_ + off2[nt];
      asm volatile("global_store_short %0, %1, off sc0" :: "v"(pA), "v"(hv) : "memory");
      asm volatile("global_store_short %0, %1, off sc1" :: "v"(pB), "v"(hv) : "memory");
    }
    asm volatile("s_waitcnt vmcnt(0)" ::: "memory");
    if (lane == 0)
      __hip_atomic_store(myf, 1u, __ATOMIC_RELAXED, __HIP_MEMORY_SCOPE_AGENT);
  }
  float4 xr0, xr1, xr2, xr3;
  {
    const float* xp = x + ((size_t)(1 + tpar) * 64 + b0 + lm) * 64;
    xr0 = *(const float4*)(xp + kg * 8);  xr1 = *(const float4*)(xp + kg * 8 + 4);
    xr2 = *(const float4*)(xp + 32 + kg * 8); xr3 = *(const float4*)(xp + 36 + kg * 8);
  }

  int bR = 0;
  for (int k = 0; k < N_ROUNDS; ++k) {
    const int bW = (bR == 2) ? 0 : bR + 1;
    const int par = k & 1;

    // ---- phase A: u for t1=2k+1 (waves 0,1) / t2=2k+2 (waves 2,3)
    {
      f32x4 au = {0.f, 0.f, 0.f, 0.f};
      au = MFMA16(cvt8(xr0, xr1), wi0, au);
      au = MFMA16(cvt8(xr2, xr3), wi1, au);
#pragma unroll
      for (int r = 0; r < 4; ++r) ubuf[par][tpar][ntu][kg * 4 + r][lm] = au[r];
    }

    // ---- phase B: tight-spin poll on my 16 producer blocks' 64 wave-flags
    {
      const unsigned tgt = (unsigned)(k + 1);
      unsigned v = __hip_atomic_load(pollp, __ATOMIC_RELAXED, __HIP_MEMORY_SCOPE_AGENT);
      while (!__all((int)(v >= tgt)))
        v = __hip_atomic_load(pollp, __ATOMIC_RELAXED, __HIP_MEMORY_SCOPE_AGENT);
    }

    // ---- phase C: (s,c) frags of K-slice [512w,+512); local half from XCD L2
    //      (sc0), cross half from LLC (sc1)
    const half_t* rb = (locw ? StA : StB) + (size_t)(bR * 4 + rep) * ST_UNIT;
    const half_t* ps0 = rb + w * 8192 + kg * 128 + lm * 8;
    const half_t* ps1 = ps0 + 2048;
    const half_t* ps2 = ps0 + 4096;
    const half_t* ps3 = ps0 + 6144;
    const half_t* pc0 = ps0 + 32768;
    const half_t* pc1 = ps1 + 32768;
    const half_t* pc2 = ps2 + 32768;
    const half_t* pc3 = ps3 + 32768;
    float4 Sr[16], Cr[16];
#define LOADS(SC)                                                         \
    asm volatile(                                                         \
        "global_load_dwordx4 %0, %32, off " SC "\n\t"                     \
        "global_load_dwordx4 %1, %32, off offset:1024 " SC "\n\t"         \
        "global_load_dwordx4 %2, %32, off offset:2048 " SC "\n\t"         \
        "global_load_dwordx4 %3, %32, off offset:3072 " SC "\n\t"         \
        "global_load_dwordx4 %4, %33, off " SC "\n\t"                     \
        "global_load_dwordx4 %5, %33, off offset:1024 " SC "\n\t"         \
        "global_load_dwordx4 %6, %33, off offset:2048 " SC "\n\t"         \
        "global_load_dwordx4 %7, %33, off offset:3072 " SC "\n\t"         \
        "global_load_dwordx4 %8, %34, off " SC "\n\t"                     \
        "global_load_dwordx4 %9, %34, off offset:1024 " SC "\n\t"         \
        "global_load_dwordx4 %10, %34, off offset:2048 " SC "\n\t"        \
        "global_load_dwordx4 %11, %34, off offset:3072 " SC "\n\t"        \
        "global_load_dwordx4 %12, %35, off " SC "\n\t"                    \
        "global_load_dwordx4 %13, %35, off offset:1024 " SC "\n\t"        \
        "global_load_dwordx4 %14, %35, off offset:2048 " SC "\n\t"        \
        "global_load_dwordx4 %15, %35, off offset:3072 " SC "\n\t"        \
        "global_load_dwordx4 %16, %36, off " SC "\n\t"                    \
        "global_load_dwordx4 %17, %36, off offset:1024 " SC "\n\t"        \
        "global_load_dwordx4 %18, %36, off offset:2048 " SC "\n\t"        \
        "global_load_dwordx4 %19, %36, off offset:3072 " SC "\n\t"        \
        "global_load_dwordx4 %20, %37, off " SC "\n\t"                    \
        "global_load_dwordx4 %21, %37, off offset:1024 " SC "\n\t"        \
        "global_load_dwordx4 %22, %37, off offset:2048 " SC "\n\t"        \
        "global_load_dwordx4 %23, %37, off offset:3072 " SC "\n\t"        \
        "global_load_dwordx4 %24, %38, off " SC "\n\t"                    \
        "global_load_dwordx4 %25, %38, off offset:1024 " SC "\n\t"        \
        "global_load_dwordx4 %26, %38, off offset:2048 " SC "\n\t"        \
        "global_load_dwordx4 %27, %38, off offset:3072 " SC "\n\t"        \
        "global_load_dwordx4 %28, %39, off " SC "\n\t"                    \
        "global_load_dwordx4 %29, %39, off offset:1024 " SC "\n\t"        \
        "global_load_dwordx4 %30, %39, off offset:2048 " SC "\n\t"        \
        "global_load_dwordx4 %31, %39, off offset:3072 " SC "\n\t"        \
        "s_waitcnt vmcnt(0)"                                              \
        : "=&v"(Sr[0]), "=&v"(Sr[1]), "=&v"(Sr[2]), "=&v"(Sr[3]),         \
          "=&v"(Sr[4]), "=&v"(Sr[5]), "=&v"(Sr[6]), "=&v"(Sr[7]),         \
          "=&v"(Sr[8]), "=&v"(Sr[9]), "=&v"(Sr[10]), "=&v"(Sr[11]),       \
          "=&v"(Sr[12]), "=&v"(Sr[13]), "=&v"(Sr[14]), "=&v"(Sr[15]),     \
          "=&v"(Cr[0]), "=&v"(Cr[1]), "=&v"(Cr[2]), "=&v"(Cr[3]),         \
          "=&v"(Cr[4]), "=&v"(Cr[5]), "=&v"(Cr[6]), "=&v"(Cr[7]),         \
          "=&v"(Cr[8]), "=&v"(Cr[9]), "=&v"(Cr[10]), "=&v"(Cr[11]),       \
          "=&v"(Cr[12]), "=&v"(Cr[13]), "=&v"(Cr[14]), "=&v"(Cr[15])      \
        : "v"(ps0), "v"(ps1), "v"(ps2), "v"(ps3),                         \
          "v"(pc0), "v"(pc1), "v"(pc2), "v"(pc3)                          \
        : "memory")
    if (locw) { LOADS("sc0"); } else { LOADS("sc1"); }
#undef LOADS

    // ---- phase D: y1 = W*s ; y23 = W*c + W^2*s   (96 MFMA)
    f32x4 y1a0 = {0.f,0.f,0.f,0.f}, y1a1 = {0.f,0.f,0.f,0.f};
    f32x4 y23a0 = {0.f,0.f,0.f,0.f}, y23a1 = {0.f,0.f,0.f,0.f};
#pragma unroll
    for (int c = 0; c < 16; ++c) {
      half8 sf = __builtin_bit_cast(half8, Sr[c]);
      half8 cf = __builtin_bit_cast(half8, Cr[c]);
      y1a0 = MFMA16(sf, wb[0][c], y1a0);
      y1a1 = MFMA16(sf, wb[1][c], y1a1);
      y23a0 = MFMA16(cf, wb[0][c], y23a0);
      y23a1 = MFMA16(cf, wb[1][c], y23a1);
      y23a0 = MFMA16(sf, w2b[0][c], y23a0);
      y23a1 = MFMA16(sf, w2b[1][c], y23a1);
    }
#pragma unroll
    for (int r = 0; r < 4; ++r) {
      ybuf[par][w][0][0][kg * 4 + r][lm] = y1a0[r];
      ybuf[par][w][0][1][kg * 4 + r][lm] = y1a1[r];
      ybuf[par][w][1][0][kg * 4 + r][lm] = y23a0[r];
      ybuf[par][w][1][1][kg * 4 + r][lm] = y23a1[r];
    }
    __syncthreads();

    // ---- phase E: combine two steps -> pack into LDS (slot-local layout,
    //      identical index math as global), then ONE dwordx4 per wave:
    //      w0: StB.s sc1 | w1: StB.c sc1 | w2: StA.s sc0 | w3: StA.c sc0
    half_t* wBA = StA + (size_t)(bW * 4 + rep) * ST_UNIT;
    half_t* wBB = StB + (size_t)(bW * 4 + rep) * ST_UNIT;
#pragma unroll
    for (int nt = 0; nt < 2; ++nt) {
      const float y1v = ybuf[par][0][0][nt][m][nn] + ybuf[par][1][0][nt][m][nn] +
                        ybuf[par][2][0][nt][m][nn] + ybuf[par][3][0][nt][m][nn];
      const float y23v = ybuf[par][0][1][nt][m][nn] + ybuf[par][1][1][nt][m][nn] +
                         ybuf[par][2][1][nt][m][nn] + ybuf[par][3][1][nt][m][nn];
      const float u1 = ubuf[par][0][nt][m][nn] + cB2[nt];
      const float u2 = ubuf[par][1][nt][m][nn] + cB2[nt];
      const float s1 = cpr[nt] + y1v;
      const float c1 = cA2[nt] * __cosf(cOm2[nt] * s1 + u1);
      const float s2 = c1 + y23v;
      const float c2 = cA2[nt] * __cosf(cOm2[nt] * s2 + u2);
      cpr[nt] = c2;
      pbufS[pix2[nt]] = (half_t)s2;
      pbufC[pix2[nt]] = (half_t)c2;
    }
    __syncthreads();
    {
      const f32x4 val = (w & 1) ? *((const f32x4*)pbufC + lane)
                                : *((const f32x4*)pbufS + lane);
      const int coff = (w & 1) ? 32768 : 0;
      const half_t* dst = ((w & 2) ? wBA : wBB) + coff + slot * 512 + lane * 8;
      if (w & 2) {
        asm volatile("global_store_dwordx4 %0, %1, off sc0" :: "v"(dst), "v"(val) : "memory");
      } else {
        asm volatile("global_store_dwordx4 %0, %1, off sc1" :: "v"(dst), "v"(val) : "memory");
      }
    }
    asm volatile("s_waitcnt vmcnt(0)" ::: "memory");
    if (lane == 0)
      __hip_atomic_store(myf, (unsigned)(k + 2), __ATOMIC_RELAXED, __HIP_MEMORY_SCOPE_AGENT);

    // ---- phase G: x prefetch for round k+1 (off the serial chain)
    {
      int t = 2 * k + 3 + tpar;
      if (t > 511) t = 511;
      const float* xp = x + ((size_t)t * 64 + b0 + lm) * 64;
      xr0 = *(const float4*)(xp + kg * 8);  xr1 = *(const float4*)(xp + kg * 8 + 4);
      xr2 = *(const float4*)(xp + 32 + kg * 8); xr3 = *(const float4*)(xp + 36 + kg * 8);
    }
    bR = bW;
  }
}

__global__ __launch_bounds__(256) void psrnn_readout_kernel(
    const float* __restrict__ Wr_w,   // [64][2048]
    const float* __restrict__ Wr_b,   // [64]
    const half_t* __restrict__ StB,   // LLC copy; final state in buf 1
    float* __restrict__ out)          // [64][64]
{
  const int tid = threadIdx.x, v = tid >> 6, lane = tid & 63;
  const int lm = lane & 15, kg = lane >> 4;
  const int rep = blockIdx.x;  // 4 blocks
  const half_t* sb = StB + (size_t)(1 * 4 + rep) * ST_UNIT;  // buf (255+1)%3 = 1

  f32x4 acc = {0.f, 0.f, 0.f, 0.f};
  for (int cg = 0; cg < 64; ++cg) {
    half8 a = *(const half8*)(sb + (size_t)cg * 512 + kg * 128 + lm * 8);
    const float* p = Wr_w + (size_t)(v * 16 + lm) * NHID + cg * 32 + kg * 8;
    half8 b = cvt8(*(const float4*)p, *(const float4*)(p + 4));
    acc = MFMA16(a, b, acc);
  }
#pragma unroll
  for (int r = 0; r < 4; ++r) {
    const int bidx = rep * 16 + kg * 4 + r;
    out[bidx * NOUT + v * 16 + lm] = acc[r] + Wr_b[v * 16 + lm];
  }
}

extern "C" void kernel_launch(void* const* d_in, const int* in_sizes, int n_in,
                              void* d_out, int out_size, void* d_ws, size_t ws_size,
                              hipStream_t stream) {
  const float* x    = (const float*)d_in[0];
  const float* Wi_w = (const float*)d_in[1];
  const float* Wi_b = (const float*)d_in[2];
  const float* Wh_w = (const float*)d_in[3];
  const float* Av   = (const float*)d_in[4];
  const float* Om   = (const float*)d_in[5];
  const float* Wr_w = (const float*)d_in[6];
  const float* Wr_b = (const float*)d_in[7];

  unsigned* flags  = (unsigned*)d_ws;
  unsigned* roster = (unsigned*)((char*)d_ws + 4096);
  half_t*   StA    = (half_t*)((char*)d_ws + (1u << 20));
  half_t*   StB    = (half_t*)((char*)d_ws + (3u << 20));
  half_t*   WT16   = (half_t*)((char*)d_ws + (8u << 20));
  half_t*   W2     = (half_t*)((char*)d_ws + (16u << 20));

  psrnn_conv_kernel<<<1024, 256, 0, stream>>>(Wh_w, WT16);
  psrnn_w2_kernel<<<256, 256, 0, stream>>>(Wh_w, WT16, W2);
  psrnn_init_kernel<<<64, 256, 0, stream>>>(flags, roster, (uint4*)StA, (uint4*)StB);
  psrnn_main_kernel<<<256, 256, 40960, stream>>>(x, Wi_w, Wi_b, Wh_w, Av, Om, W2,
                                                 flags, roster, StA, StB);
  psrnn_readout_kernel<<<4, 256, 0, stream>>>(Wr_w, Wr_b, StB, (float*)d_out);
}

// Round 8
// 1229.630 us; speedup vs baseline: 1.0756x; 1.0756x over previous
//
#include <hip/hip_runtime.h>

// psRNN round 15: revert main to EXACT r7 (proven 1084us dispatch) + trim the
// ~127us non-main overhead. Evidence base: round latency is invariant at
// ~4.0-4.2us across five structurally different designs (r7/r9/r11/r12/r14)
// regardless of MFMA count, broadcast volume, transport scope, poll pressure,
// publish width => grid-wide handoff floor (~9.7k cy: drain + LLC flag RTT +
// detect + 64-block straggler spread). r7's W^2 2-step amortization is the
// algebraic max over that floor; the main loop is latency-floored.
// This round reclaims the predictable part: (a) DELETE the conv kernel --
// fold the W->W^T f16 transpose into w2's LDS staging (load 32x128 fp32
// sub-blocks of W coalesced, scalar-transpose to f16 Bs; bit-identical
// numerics: same single fp32->f16 rounding); (b) fold init into w2's first
// 64 blocks; (c) 5 launches -> 3. Main byte-identical to r7.
// Predicted: main counters unchanged (1084us, MfmaUtil 16.3, FETCH 126MB,
// WRITE 141MB), absmax 0.015625 identical, total 1211 -> ~1155-1180us.
// If >= 1205: overhead model wrong -> declare latency floor next round.

typedef _Float16 half_t;
typedef _Float16 half8 __attribute__((ext_vector_type(8)));
typedef float f32x4 __attribute__((ext_vector_type(4)));

#define NHID 2048
#define NOUT 64
#define ST_UNIT 65536   // halfs per (buf,rep): s [0,32768) + c [32768,65536)
#define N_ROUNDS 256

#define MFMA16(A, B, C) __builtin_amdgcn_mfma_f32_16x16x32_f16(A, B, C, 0, 0, 0)

// ws layout (bytes):
//   [0, 4096)       : flags  uint[4][256]  ([rep][slot*4+wave], monotonic)
//   [4096, 4160)    : roster uint[8]       (per-XCD block counter)
//   [1M, 1M+1.5M)   : StA  half[3][4][ST_UNIT]  (sc0 / XCD-L2 copy)
//   [3M, 3M+1.5M)   : StB  half[3][4][ST_UNIT]  (sc1 / LLC copy)
//   [16M, 24M)      : W2   half[2048][2048]

__device__ __forceinline__ half8 cvt8(float4 lo, float4 hi) {
  half8 h;
  h[0] = (half_t)lo.x; h[1] = (half_t)lo.y; h[2] = (half_t)lo.z; h[3] = (half_t)lo.w;
  h[4] = (half_t)hi.x; h[5] = (half_t)hi.y; h[6] = (half_t)hi.z; h[7] = (half_t)hi.w;
  return h;
}

// W2 = f16( f16(W) @ f16(W) ), 128x128 tiles. B-chunk (W^T sub-block) staged
// in LDS via in-kernel transpose of fp32 W (conv kernel deleted). Blocks
// 0..63 also perform state/flag init (init kernel deleted).
__global__ __launch_bounds__(256) void psrnn_w2_kernel(
    const float* __restrict__ Wh, half_t* __restrict__ W2,
    unsigned* __restrict__ flags, unsigned* __restrict__ roster,
    uint4* __restrict__ stA, uint4* __restrict__ stB) {
  __shared__ half_t Bs[128][40];  // pad 40: 16B-aligned frags, spread banks
  const int bi = blockIdx.x & 15, bj = blockIdx.x >> 4;
  const int tid = threadIdx.x, w = tid >> 6, lane = tid & 63;
  const int lm = lane & 15, kg = lane >> 4;

  // ---- fused init (blocks 0..63): buf0 s := fp16 1.0 both copies; flags 0
  if (blockIdx.x < 64) {
    const int g = blockIdx.x * 256 + tid;  // 16384 threads total
    uint4 v; v.x = 0x3C003C00u; v.y = 0x3C003C00u; v.z = 0x3C003C00u; v.w = 0x3C003C00u;
    const int rep = g >> 12, local = g & 4095;
    stA[rep * (ST_UNIT / 8) + local] = v;
    stB[rep * (ST_UNIT / 8) + local] = v;
    if (g < 1024) flags[g] = 0;
    else if (g < 1032) roster[g - 1024] = 0;
  }

  // ---- staging decomposition: thread loads W[c*32+kr][bj*128+cs .. +16]
  const int kr = tid >> 3, cs = (tid & 7) * 16;

  f32x4 acc[2][8];
#pragma unroll
  for (int mt = 0; mt < 2; ++mt)
#pragma unroll
    for (int nt = 0; nt < 8; ++nt) acc[mt][nt] = (f32x4){0.f, 0.f, 0.f, 0.f};

  for (int c = 0; c < 64; ++c) {
    __syncthreads();
    {
      const float* src = Wh + (size_t)(c * 32 + kr) * NHID + bj * 128 + cs;
      float4 v0 = *(const float4*)(src);
      float4 v1 = *(const float4*)(src + 4);
      float4 v2 = *(const float4*)(src + 8);
      float4 v3 = *(const float4*)(src + 12);
      Bs[cs +  0][kr] = (half_t)v0.x; Bs[cs +  1][kr] = (half_t)v0.y;
      Bs[cs +  2][kr] = (half_t)v0.z; Bs[cs +  3][kr] = (half_t)v0.w;
      Bs[cs +  4][kr] = (half_t)v1.x; Bs[cs +  5][kr] = (half_t)v1.y;
      Bs[cs +  6][kr] = (half_t)v1.z; Bs[cs +  7][kr] = (half_t)v1.w;
      Bs[cs +  8][kr] = (half_t)v2.x; Bs[cs +  9][kr] = (half_t)v2.y;
      Bs[cs + 10][kr] = (half_t)v2.z; Bs[cs + 11][kr] = (half_t)v2.w;
      Bs[cs + 12][kr] = (half_t)v3.x; Bs[cs + 13][kr] = (half_t)v3.y;
      Bs[cs + 14][kr] = (half_t)v3.z; Bs[cs + 15][kr] = (half_t)v3.w;
    }
    __syncthreads();
    const float* pa0 = Wh + (size_t)(bi * 128 + w * 32 + lm) * NHID + c * 32 + kg * 8;
    const float* pa1 = pa0 + (size_t)16 * NHID;
    half8 a0 = cvt8(*(const float4*)pa0, *(const float4*)(pa0 + 4));
    half8 a1 = cvt8(*(const float4*)pa1, *(const float4*)(pa1 + 4));
#pragma unroll
    for (int nt = 0; nt < 8; ++nt) {
      half8 b = *(const half8*)&Bs[nt * 16 + lm][kg * 8];
      acc[0][nt] = MFMA16(a0, b, acc[0][nt]);
      acc[1][nt] = MFMA16(a1, b, acc[1][nt]);
    }
  }
#pragma unroll
  for (int mt = 0; mt < 2; ++mt)
#pragma unroll
    for (int nt = 0; nt < 8; ++nt)
#pragma unroll
      for (int r = 0; r < 4; ++r)
        W2[(size_t)(bi * 128 + w * 32 + mt * 16 + kg * 4 + r) * NHID +
           bj * 128 + nt * 16 + lm] = (half_t)acc[mt][nt][r];
}

__global__ __launch_bounds__(256, 1) void psrnn_main_kernel(
    const float* __restrict__ x,      // [512][64][64]
    const float* __restrict__ Wi_w,   // [2048][64]
    const float* __restrict__ Wi_b,   // [2048]
    const float* __restrict__ Wh_w,   // [2048][2048]
    const float* __restrict__ Av,     // [2048]
    const float* __restrict__ Om,     // [2048]
    const half_t* __restrict__ W2,    // [2048][2048] f16
    unsigned* __restrict__ flags,
    unsigned* __restrict__ roster,
    half_t* __restrict__ StA,         // sc0 / XCD-L2 copy
    half_t* __restrict__ StB)         // sc1 / LLC copy
{
  extern __shared__ char lds_force[];        // +40KB dyn: forces 1 block/CU
  __shared__ float ybuf[2][4][2][2][16][18]; // [par][wave][arr][nt][m][n]
  __shared__ float ubuf[2][2][2][16][18];    // [par][t'][nt][m][n]
  __shared__ unsigned slot_sh;
  (void)lds_force;

  const int tid = threadIdx.x, w = tid >> 6, lane = tid & 63;
  const int lm = lane & 15, kg = lane >> 4;

  unsigned xcd;
  asm volatile("s_getreg_b32 %0, hwreg(HW_REG_XCC_ID)" : "=s"(xcd));
  const int rep    = (int)(xcd & 3u);
  const int halfId = (int)((xcd >> 2) & 1u);
  if (tid == 0) slot_sh = (unsigned)(halfId * 32) + (atomicAdd(&roster[xcd & 7u], 1u) & 31u);
  __syncthreads();
  const int slot = (int)slot_sh;
  const int n0 = slot * 32, b0 = rep * 16;
  const bool locw = ((w >> 1) == halfId);  // my producers are on my XCD
  const int tpar = w >> 1, ntu = w & 1;    // u-duty: wave -> (timestep, nt)

  // ---- W, W2 B-frags: rows n0+16nt+lm, K = 512w + 32c + kg*8..
  half8 wb[2][16], w2b[2][16];
#pragma unroll
  for (int nt = 0; nt < 2; ++nt)
#pragma unroll
    for (int c = 0; c < 16; ++c) {
      const float* p = Wh_w + (size_t)(n0 + nt * 16 + lm) * NHID + (w * 512 + c * 32 + kg * 8);
      wb[nt][c] = cvt8(*(const float4*)p, *(const float4*)(p + 4));
      w2b[nt][c] = *(const half8*)(W2 + (size_t)(n0 + nt * 16 + lm) * NHID +
                                   (w * 512 + c * 32 + kg * 8));
    }
  half8 wi0, wi1;
  {
    const float* p = Wi_w + (size_t)(n0 + ntu * 16 + lm) * 64 + kg * 8;
    wi0 = cvt8(*(const float4*)p, *(const float4*)(p + 4));
    wi1 = cvt8(*(const float4*)(p + 32), *(const float4*)(p + 36));
  }

  // ---- combiner constants: thread owns (batch m, neurons n0+nt*16+nn)
  const int m = tid >> 4, nn = tid & 15;
  float cA2[2], cOm2[2], cB2[2];
  int off2[2];
#pragma unroll
  for (int nt = 0; nt < 2; ++nt) {
    const int ng = n0 + nt * 16 + nn;
    cA2[nt] = Av[ng]; cOm2[nt] = Om[ng]; cB2[nt] = Wi_b[ng];
    off2[nt] = ((slot * 4 + nt * 2 + (nn >> 3)) * 16 + m) * 8 + (nn & 7);
  }
  float cpr[2];

  unsigned* const pollp = flags + rep * 256 + w * 64 + lane;  // 64 producer waves
  unsigned* const myf   = flags + rep * 256 + slot * 4 + w;

  // ---- preloop: u_0 (waves 0,1), publish c_0 to buf0 (both copies), flag=1
  if (w < 2) {
    const float* xp = x + (size_t)(b0 + lm) * 64;
    float4 a0 = *(const float4*)(xp + kg * 8), a1 = *(const float4*)(xp + kg * 8 + 4);
    float4 a2 = *(const float4*)(xp + 32 + kg * 8), a3 = *(const float4*)(xp + 36 + kg * 8);
    f32x4 au = {0.f, 0.f, 0.f, 0.f};
    au = MFMA16(cvt8(a0, a1), wi0, au);
    au = MFMA16(cvt8(a2, a3), wi1, au);
#pragma unroll
    for (int r = 0; r < 4; ++r) ubuf[0][0][ntu][kg * 4 + r][lm] = au[r];
  }
  __syncthreads();
  {
    half_t* cA_ = StA + (size_t)rep * ST_UNIT + 32768;
    half_t* cB_ = StB + (size_t)rep * ST_UNIT + 32768;
#pragma unroll
    for (int nt = 0; nt < 2; ++nt) {
      const float u0 = ubuf[0][0][nt][m][nn] + cB2[nt];
      cpr[nt] = cA2[nt] * __cosf(cOm2[nt] * 1.0f + u0);
      unsigned hv = (unsigned)__builtin_bit_cast(unsigned short, (half_t)cpr[nt]);
      const half_t* pA = cA_ + off2[nt];
      const half_t* pB = cB_ + off2[nt];
      asm volatile("global_store_short %0, %1, off sc0" :: "v"(pA), "v"(hv) : "memory");
      asm volatile("global_store_short %0, %1, off sc1" :: "v"(pB), "v"(hv) : "memory");
    }
    asm volatile("s_waitcnt vmcnt(0)" ::: "memory");
    if (lane == 0)
      __hip_atomic_store(myf, 1u, __ATOMIC_RELAXED, __HIP_MEMORY_SCOPE_AGENT);
  }
  float4 xr0, xr1, xr2, xr3;
  {
    const float* xp = x + ((size_t)(1 + tpar) * 64 + b0 + lm) * 64;
    xr0 = *(const float4*)(xp + kg * 8);  xr1 = *(const float4*)(xp + kg * 8 + 4);
    xr2 = *(const float4*)(xp + 32 + kg * 8); xr3 = *(const float4*)(xp + 36 + kg * 8);
  }

  int bR = 0;
  for (int k = 0; k < N_ROUNDS; ++k) {
    const int bW = (bR == 2) ? 0 : bR + 1;
    const int par = k & 1;

    // ---- phase A: u for t1=2k+1 (waves 0,1) / t2=2k+2 (waves 2,3)
    {
      f32x4 au = {0.f, 0.f, 0.f, 0.f};
      au = MFMA16(cvt8(xr0, xr1), wi0, au);
      au = MFMA16(cvt8(xr2, xr3), wi1, au);
#pragma unroll
      for (int r = 0; r < 4; ++r) ubuf[par][tpar][ntu][kg * 4 + r][lm] = au[r];
    }

    // ---- phase B: tight-spin poll on my 16 producer blocks' 64 wave-flags
    {
      const unsigned tgt = (unsigned)(k + 1);
      unsigned v = __hip_atomic_load(pollp, __ATOMIC_RELAXED, __HIP_MEMORY_SCOPE_AGENT);
      while (!__all((int)(v >= tgt)))
        v = __hip_atomic_load(pollp, __ATOMIC_RELAXED, __HIP_MEMORY_SCOPE_AGENT);
    }

    // ---- phase C: (s,c) frags of K-slice [512w,+512); local half from XCD L2
    //      (sc0, r2/r5-proven), cross half from LLC (sc1, r6-proven)
    const half_t* rb = (locw ? StA : StB) + (size_t)(bR * 4 + rep) * ST_UNIT;
    const half_t* ps0 = rb + w * 8192 + kg * 128 + lm * 8;
    const half_t* ps1 = ps0 + 2048;
    const half_t* ps2 = ps0 + 4096;
    const half_t* ps3 = ps0 + 6144;
    const half_t* pc0 = ps0 + 32768;
    const half_t* pc1 = ps1 + 32768;
    const half_t* pc2 = ps2 + 32768;
    const half_t* pc3 = ps3 + 32768;
    float4 Sr[16], Cr[16];
#define LOADS(SC)                                                         \
    asm volatile(                                                         \
        "global_load_dwordx4 %0, %32, off " SC "\n\t"                     \
        "global_load_dwordx4 %1, %32, off offset:1024 " SC "\n\t"         \
        "global_load_dwordx4 %2, %32, off offset:2048 " SC "\n\t"         \
        "global_load_dwordx4 %3, %32, off offset:3072 " SC "\n\t"         \
        "global_load_dwordx4 %4, %33, off " SC "\n\t"                     \
        "global_load_dwordx4 %5, %33, off offset:1024 " SC "\n\t"         \
        "global_load_dwordx4 %6, %33, off offset:2048 " SC "\n\t"         \
        "global_load_dwordx4 %7, %33, off offset:3072 " SC "\n\t"         \
        "global_load_dwordx4 %8, %34, off " SC "\n\t"                     \
        "global_load_dwordx4 %9, %34, off offset:1024 " SC "\n\t"         \
        "global_load_dwordx4 %10, %34, off offset:2048 " SC "\n\t"        \
        "global_load_dwordx4 %11, %34, off offset:3072 " SC "\n\t"        \
        "global_load_dwordx4 %12, %35, off " SC "\n\t"                    \
        "global_load_dwordx4 %13, %35, off offset:1024 " SC "\n\t"        \
        "global_load_dwordx4 %14, %35, off offset:2048 " SC "\n\t"        \
        "global_load_dwordx4 %15, %35, off offset:3072 " SC "\n\t"        \
        "global_load_dwordx4 %16, %36, off " SC "\n\t"                    \
        "global_load_dwordx4 %17, %36, off offset:1024 " SC "\n\t"        \
        "global_load_dwordx4 %18, %36, off offset:2048 " SC "\n\t"        \
        "global_load_dwordx4 %19, %36, off offset:3072 " SC "\n\t"        \
        "global_load_dwordx4 %20, %37, off " SC "\n\t"                    \
        "global_load_dwordx4 %21, %37, off offset:1024 " SC "\n\t"        \
        "global_load_dwordx4 %22, %37, off offset:2048 " SC "\n\t"        \
        "global_load_dwordx4 %23, %37, off offset:3072 " SC "\n\t"        \
        "global_load_dwordx4 %24, %38, off " SC "\n\t"                    \
        "global_load_dwordx4 %25, %38, off offset:1024 " SC "\n\t"        \
        "global_load_dwordx4 %26, %38, off offset:2048 " SC "\n\t"        \
        "global_load_dwordx4 %27, %38, off offset:3072 " SC "\n\t"        \
        "global_load_dwordx4 %28, %39, off " SC "\n\t"                    \
        "global_load_dwordx4 %29, %39, off offset:1024 " SC "\n\t"        \
        "global_load_dwordx4 %30, %39, off offset:2048 " SC "\n\t"        \
        "global_load_dwordx4 %31, %39, off offset:3072 " SC "\n\t"        \
        "s_waitcnt vmcnt(0)"                                              \
        : "=&v"(Sr[0]), "=&v"(Sr[1]), "=&v"(Sr[2]), "=&v"(Sr[3]),         \
          "=&v"(Sr[4]), "=&v"(Sr[5]), "=&v"(Sr[6]), "=&v"(Sr[7]),         \
          "=&v"(Sr[8]), "=&v"(Sr[9]), "=&v"(Sr[10]), "=&v"(Sr[11]),       \
          "=&v"(Sr[12]), "=&v"(Sr[13]), "=&v"(Sr[14]), "=&v"(Sr[15]),     \
          "=&v"(Cr[0]), "=&v"(Cr[1]), "=&v"(Cr[2]), "=&v"(Cr[3]),         \
          "=&v"(Cr[4]), "=&v"(Cr[5]), "=&v"(Cr[6]), "=&v"(Cr[7]),         \
          "=&v"(Cr[8]), "=&v"(Cr[9]), "=&v"(Cr[10]), "=&v"(Cr[11]),       \
          "=&v"(Cr[12]), "=&v"(Cr[13]), "=&v"(Cr[14]), "=&v"(Cr[15])      \
        : "v"(ps0), "v"(ps1), "v"(ps2), "v"(ps3),                         \
          "v"(pc0), "v"(pc1), "v"(pc2), "v"(pc3)                          \
        : "memory")
    if (locw) { LOADS("sc0"); } else { LOADS("sc1"); }
#undef LOADS

    // ---- phase D: y1 = W*s ; y23 = W*c + W^2*s   (96 MFMA)
    f32x4 y1a0 = {0.f,0.f,0.f,0.f}, y1a1 = {0.f,0.f,0.f,0.f};
    f32x4 y23a0 = {0.f,0.f,0.f,0.f}, y23a1 = {0.f,0.f,0.f,0.f};
#pragma unroll
    for (int c = 0; c < 16; ++c) {
      half8 sf = __builtin_bit_cast(half8, Sr[c]);
      half8 cf = __builtin_bit_cast(half8, Cr[c]);
      y1a0 = MFMA16(sf, wb[0][c], y1a0);
      y1a1 = MFMA16(sf, wb[1][c], y1a1);
      y23a0 = MFMA16(cf, wb[0][c], y23a0);
      y23a1 = MFMA16(cf, wb[1][c], y23a1);
      y23a0 = MFMA16(sf, w2b[0][c], y23a0);
      y23a1 = MFMA16(sf, w2b[1][c], y23a1);
    }
#pragma unroll
    for (int r = 0; r < 4; ++r) {
      ybuf[par][w][0][0][kg * 4 + r][lm] = y1a0[r];
      ybuf[par][w][0][1][kg * 4 + r][lm] = y1a1[r];
      ybuf[par][w][1][0][kg * 4 + r][lm] = y23a0[r];
      ybuf[par][w][1][1][kg * 4 + r][lm] = y23a1[r];
    }
    __syncthreads();  // the only barrier per round

    // ---- phase E: combine two steps, dual-publish (s,c), flag
    half_t* wBA = StA + (size_t)(bW * 4 + rep) * ST_UNIT;
    half_t* wBB = StB + (size_t)(bW * 4 + rep) * ST_UNIT;
#pragma unroll
    for (int nt = 0; nt < 2; ++nt) {
      const float y1v = ybuf[par][0][0][nt][m][nn] + ybuf[par][1][0][nt][m][nn] +
                        ybuf[par][2][0][nt][m][nn] + ybuf[par][3][0][nt][m][nn];
      const float y23v = ybuf[par][0][1][nt][m][nn] + ybuf[par][1][1][nt][m][nn] +
                         ybuf[par][2][1][nt][m][nn] + ybuf[par][3][1][nt][m][nn];
      const float u1 = ubuf[par][0][nt][m][nn] + cB2[nt];
      const float u2 = ubuf[par][1][nt][m][nn] + cB2[nt];
      const float s1 = cpr[nt] + y1v;
      const float c1 = cA2[nt] * __cosf(cOm2[nt] * s1 + u1);
      const float s2 = c1 + y23v;
      const float c2 = cA2[nt] * __cosf(cOm2[nt] * s2 + u2);
      cpr[nt] = c2;
      unsigned hs = (unsigned)__builtin_bit_cast(unsigned short, (half_t)s2);
      unsigned hc = (unsigned)__builtin_bit_cast(unsigned short, (half_t)c2);
      const half_t* sA = wBA + off2[nt];
      const half_t* sB = wBB + off2[nt];
      const half_t* cAp = wBA + 32768 + off2[nt];
      const half_t* cBp = wBB + 32768 + off2[nt];
      asm volatile("global_store_short %0, %1, off sc0" :: "v"(sA), "v"(hs) : "memory");
      asm volatile("global_store_short %0, %1, off sc1" :: "v"(sB), "v"(hs) : "memory");
      asm volatile("global_store_short %0, %1, off sc0" :: "v"(cAp), "v"(hc) : "memory");
      asm volatile("global_store_short %0, %1, off sc1" :: "v"(cBp), "v"(hc) : "memory");
    }
    asm volatile("s_waitcnt vmcnt(0)" ::: "memory");
    if (lane == 0)
      __hip_atomic_store(myf, (unsigned)(k + 2), __ATOMIC_RELAXED, __HIP_MEMORY_SCOPE_AGENT);

    // ---- phase G: x prefetch for round k+1 (off the serial chain)
    {
      int t = 2 * k + 3 + tpar;
      if (t > 511) t = 511;
      const float* xp = x + ((size_t)t * 64 + b0 + lm) * 64;
      xr0 = *(const float4*)(xp + kg * 8);  xr1 = *(const float4*)(xp + kg * 8 + 4);
      xr2 = *(const float4*)(xp + 32 + kg * 8); xr3 = *(const float4*)(xp + 36 + kg * 8);
    }
    bR = bW;
  }
}

__global__ __launch_bounds__(256) void psrnn_readout_kernel(
    const float* __restrict__ Wr_w,   // [64][2048]
    const float* __restrict__ Wr_b,   // [64]
    const half_t* __restrict__ StB,   // LLC copy; final state in buf 1
    float* __restrict__ out)          // [64][64]
{
  const int tid = threadIdx.x, v = tid >> 6, lane = tid & 63;
  const int lm = lane & 15, kg = lane >> 4;
  const int rep = blockIdx.x;  // 4 blocks
  const half_t* sb = StB + (size_t)(1 * 4 + rep) * ST_UNIT;  // buf (255+1)%3 = 1

  f32x4 acc = {0.f, 0.f, 0.f, 0.f};
  for (int cg = 0; cg < 64; ++cg) {
    half8 a = *(const half8*)(sb + (size_t)cg * 512 + kg * 128 + lm * 8);
    const float* p = Wr_w + (size_t)(v * 16 + lm) * NHID + cg * 32 + kg * 8;
    half8 b = cvt8(*(const float4*)p, *(const float4*)(p + 4));
    acc = MFMA16(a, b, acc);
  }
#pragma unroll
  for (int r = 0; r < 4; ++r) {
    const int bidx = rep * 16 + kg * 4 + r;
    out[bidx * NOUT + v * 16 + lm] = acc[r] + Wr_b[v * 16 + lm];
  }
}

extern "C" void kernel_launch(void* const* d_in, const int* in_sizes, int n_in,
                              void* d_out, int out_size, void* d_ws, size_t ws_size,
                              hipStream_t stream) {
  const float* x    = (const float*)d_in[0];
  const float* Wi_w = (const float*)d_in[1];
  const float* Wi_b = (const float*)d_in[2];
  const float* Wh_w = (const float*)d_in[3];
  const float* Av   = (const float*)d_in[4];
  const float* Om   = (const float*)d_in[5];
  const float* Wr_w = (const float*)d_in[6];
  const float* Wr_b = (const float*)d_in[7];

  unsigned* flags  = (unsigned*)d_ws;
  unsigned* roster = (unsigned*)((char*)d_ws + 4096);
  half_t*   StA    = (half_t*)((char*)d_ws + (1u << 20));
  half_t*   StB    = (half_t*)((char*)d_ws + (3u << 20));
  half_t*   W2     = (half_t*)((char*)d_ws + (16u << 20));

  psrnn_w2_kernel<<<256, 256, 0, stream>>>(Wh_w, W2, flags, roster,
                                           (uint4*)StA, (uint4*)StB);
  psrnn_main_kernel<<<256, 256, 40960, stream>>>(x, Wi_w, Wi_b, Wh_w, Av, Om, W2,
                                                 flags, roster, StA, StB);
  psrnn_readout_kernel<<<4, 256, 0, stream>>>(Wr_w, Wr_b, StB, (float*)d_out);
}